// Round 5
// baseline (455.963 us; speedup 1.0000x reference)
//
#include <hip/hip_runtime.h>
#include <hip/hip_bf16.h>

#define N_NODES   100000
#define N_EDGES   1600000
#define N_GRAPHS  1024
#define EMB       32
#define HID       64
#define N_CLASSES 10
#define SCAN_BLOCKS 391   // ceil(100000/256)
#define NCOMBO 153        // 17 shape ids x 9 color ids
#define NPASS 8           // fill dst-range passes (100000 = 8 * 12500)
#define PASS_W 12500

// ---------------- degree count (in-degree over dst) ----------------
__global__ __launch_bounds__(256) void deg_kernel(const int* __restrict__ dst,
                                                  int* __restrict__ degi) {
    int e = blockIdx.x * 256 + threadIdx.x;
    if (e < N_EDGES) atomicAdd(&degi[dst[e]], 1);
}

// ---------------- prep: pk[v] = v*153 + combo; dis = rsqrt(1+deg); graph counts ----------------
__global__ __launch_bounds__(256) void prep_kernel(
    const int* __restrict__ degi, const int* __restrict__ sid,
    const int* __restrict__ cid, const int* __restrict__ batch,
    int* __restrict__ pk, float* __restrict__ dis, int* __restrict__ cnt) {
    int v = blockIdx.x * 256 + threadIdx.x;
    if (v < N_NODES) {
        dis[v] = rsqrtf(1.0f + (float)degi[v]);
        pk[v] = v * NCOMBO + sid[v] * 9 + cid[v];
        atomicAdd(&cnt[batch[v]], 1);
    }
}

// ---------------- combined table: TC[s*9+c][j] = (st[s]@W1)[j] + (ct[c]@W1)[j] ----------------
__global__ __launch_bounds__(64) void tc_kernel(
    const float* __restrict__ st, const float* __restrict__ ct,
    const float* __restrict__ W1, float* __restrict__ TC) {
    int r = blockIdx.x, j = threadIdx.x;
    int s = r / 9, c = r % 9;
    float acc = 0.0f;
    if (s != 0) {
#pragma unroll
        for (int k = 0; k < EMB; ++k) acc = fmaf(st[s * EMB + k], W1[k * HID + j], acc);
    }
    if (c != 0) {
#pragma unroll
        for (int k = 0; k < EMB; ++k) acc = fmaf(ct[c * EMB + k], W1[k * HID + j], acc);
    }
    TC[r * HID + j] = acc;
}

// ---------------- 3-pass exclusive scan of degrees -> rowptr ----------------
__global__ __launch_bounds__(256) void scanA_kernel(const int* __restrict__ degi,
                                                    int* __restrict__ rowptr,
                                                    int* __restrict__ bsum) {
    __shared__ int s[256];
    int t = threadIdx.x, b = blockIdx.x;
    int v = b * 256 + t;
    int d = (v < N_NODES) ? degi[v] : 0;
    s[t] = d; __syncthreads();
#pragma unroll
    for (int off = 1; off < 256; off <<= 1) {
        int x = (t >= off) ? s[t - off] : 0;
        __syncthreads();
        s[t] += x;
        __syncthreads();
    }
    if (v < N_NODES) rowptr[v] = s[t] - d;
    if (t == 255) bsum[b] = s[255];
}

__global__ __launch_bounds__(512) void scanB_kernel(int* __restrict__ bsum) {
    __shared__ int s[512];
    int t = threadIdx.x;
    int d = (t < SCAN_BLOCKS) ? bsum[t] : 0;
    s[t] = d; __syncthreads();
#pragma unroll
    for (int off = 1; off < 512; off <<= 1) {
        int x = (t >= off) ? s[t - off] : 0;
        __syncthreads();
        s[t] += x;
        __syncthreads();
    }
    if (t < SCAN_BLOCKS) bsum[t] = s[t] - d;
}

__global__ __launch_bounds__(256) void scanC_kernel(int* __restrict__ rowptr,
                                                    int* __restrict__ cursor,
                                                    const int* __restrict__ bsum) {
    int t = threadIdx.x, b = blockIdx.x;
    int v = b * 256 + t;
    if (v < N_NODES) {
        int r = rowptr[v] + bsum[b];
        rowptr[v] = r;
        cursor[v] = r;
    }
    if (b == 0 && t == 0) rowptr[N_NODES] = N_EDGES;
}

// ---------------- CSR fill, dst-range partitioned (gridDim.y = pass) ----------------
// Each pass scatters only edges whose dst lies in an 800KB CSR window -> writes
// stay L2-resident and lines are fully populated before writeback.
__global__ __launch_bounds__(256) void fill_kernel(
    const int* __restrict__ src, const int* __restrict__ dst,
    const int* __restrict__ pk, int* __restrict__ cursor,
    int* __restrict__ epack) {
    int e = blockIdx.x * 256 + threadIdx.x;   // grid.x*256 == N_EDGES exactly
    int d = dst[e];
    int lo = blockIdx.y * PASS_W;
    if (d >= lo && d < lo + PASS_W) {
        int key = pk[src[e]];
        int pos = atomicAdd(&cursor[d], 1);
        epack[pos] = key;
    }
}

// ---------------- layer-1 aggregate from combined table -> x1 ----------------
// 4 waves/block, 4 nodes/wave (grid 6250); lane = channel; edge stream scalarized.
__global__ __launch_bounds__(256) void agg1_kernel(
    const int* __restrict__ epack, const int* __restrict__ rowptr,
    const int* __restrict__ pk, const float* __restrict__ dis,
    const float* __restrict__ TC, const float* __restrict__ b1,
    float* __restrict__ x1) {
    __shared__ __align__(16) float TCs[NCOMBO * HID];   // 39,168 B
    int t = threadIdx.x;
    {
        const float4* s4 = (const float4*)TC;
        float4* d4 = (float4*)TCs;
        for (int i = t; i < NCOMBO * HID / 4; i += 256) d4[i] = s4[i];
    }
    __syncthreads();
    int lane = t & 63, w = t >> 6;
    float bias = b1[lane];
    int v0 = (blockIdx.x * 4 + w) * 4;
    for (int n = 0; n < 4; ++n) {
        int v = v0 + n;
        int e  = __builtin_amdgcn_readfirstlane(rowptr[v]);
        int e1 = __builtin_amdgcn_readfirstlane(rowptr[v + 1]);
        float acc = 0.0f;
        for (; e + 8 <= e1; e += 8) {
            unsigned key[8];
#pragma unroll
            for (int i = 0; i < 8; ++i) key[i] = (unsigned)epack[e + i];
            float w8[8]; unsigned cb8[8];
#pragma unroll
            for (int i = 0; i < 8; ++i) {
                unsigned s = key[i] / 153u;
                cb8[i] = key[i] - s * 153u;
                w8[i] = dis[s];
            }
#pragma unroll
            for (int i = 0; i < 8; ++i)
                acc = fmaf(w8[i], TCs[cb8[i] * HID + lane], acc);
        }
        for (; e < e1; ++e) {
            unsigned k = (unsigned)epack[e];
            unsigned s = k / 153u;
            acc = fmaf(dis[s], TCs[(k - s * 153u) * HID + lane], acc);
        }
        unsigned kv = (unsigned)pk[v];
        float dv = dis[v];
        float hv = TCs[(kv - (kv / 153u) * 153u) * HID + lane];
        float val = dv * fmaf(hv, dv, acc) + bias;
        x1[(size_t)v * HID + lane] = val > 0.0f ? val : 0.0f;
    }
}

// ---------------- mm2 in place: x[v] = x[v] @ W2; W2 column held in 64 VGPRs ----------------
__global__ __launch_bounds__(256, 1) void mm2_kernel(float* __restrict__ x,
                                                     const float* __restrict__ W2) {
    __shared__ __align__(16) float xs[4][HID];
    int t = threadIdx.x, lane = t & 63, w = t >> 6;
    float wcol[HID];
#pragma unroll
    for (int k = 0; k < HID; ++k) wcol[k] = W2[k * HID + lane];
    int v0 = (blockIdx.x * 4 + w) * 16;
    for (int n = 0; n < 16; ++n) {
        int v = v0 + n;
        if (v >= N_NODES) return;
        xs[w][lane] = x[(size_t)v * HID + lane];
        float acc = 0.0f;
#pragma unroll
        for (int k4 = 0; k4 < HID / 4; ++k4) {
            float4 xv = *(const float4*)(&xs[w][k4 * 4]);
            acc = fmaf(xv.x, wcol[k4 * 4 + 0], acc);
            acc = fmaf(xv.y, wcol[k4 * 4 + 1], acc);
            acc = fmaf(xv.z, wcol[k4 * 4 + 2], acc);
            acc = fmaf(xv.w, wcol[k4 * 4 + 3], acc);
        }
        x[(size_t)v * HID + lane] = acc;
    }
}

// ---------------- layer-2 aggregate + fused mean-pool accumulation ----------------
__global__ __launch_bounds__(256) void agg2_pool_kernel(
    const int* __restrict__ epack, const int* __restrict__ rowptr,
    const float* __restrict__ h2, const float* __restrict__ dis,
    const float* __restrict__ b2, const int* __restrict__ batch,
    float* __restrict__ pooled) {
    int t = threadIdx.x, lane = t & 63;
    int v = blockIdx.x * 4 + (t >> 6);
    int e  = __builtin_amdgcn_readfirstlane(rowptr[v]);
    int e1 = __builtin_amdgcn_readfirstlane(rowptr[v + 1]);
    float acc = 0.0f;
    for (; e + 8 <= e1; e += 8) {
        unsigned key[8];
#pragma unroll
        for (int i = 0; i < 8; ++i) key[i] = (unsigned)epack[e + i];
        float g[8], w8[8];
#pragma unroll
        for (int i = 0; i < 8; ++i) {
            unsigned s = key[i] / 153u;
            w8[i] = dis[s];
            g[i] = h2[(size_t)s * HID + lane];
        }
#pragma unroll
        for (int i = 0; i < 8; ++i) acc = fmaf(w8[i], g[i], acc);
    }
    for (; e < e1; ++e) {
        unsigned k = (unsigned)epack[e];
        unsigned s = k / 153u;
        acc = fmaf(dis[s], h2[(size_t)s * HID + lane], acc);
    }
    float dv = dis[v];
    float val = dv * fmaf(h2[(size_t)v * HID + lane], dv, acc) + b2[lane];
    val = val > 0.0f ? val : 0.0f;
    unsafeAtomicAdd(&pooled[batch[v] * HID + lane], val);
}

// ---------------- logits ----------------
__global__ __launch_bounds__(64) void logits_kernel(
    const float* __restrict__ pooled, const int* __restrict__ cnt,
    const float* __restrict__ Wl, const float* __restrict__ bl,
    float* __restrict__ out) {
    __shared__ float row[HID];
    int g = blockIdx.x, t = threadIdx.x;
    int c = cnt[g]; if (c < 1) c = 1;
    row[t] = pooled[g * HID + t] / (float)c;
    __syncthreads();
    if (t < N_CLASSES) {
        float acc = bl[t];
#pragma unroll
        for (int k = 0; k < HID; ++k) acc = fmaf(row[k], Wl[k * N_CLASSES + t], acc);
        out[g * N_CLASSES + t] = acc;
    }
}

extern "C" void kernel_launch(void* const* d_in, const int* in_sizes, int n_in,
                              void* d_out, int out_size, void* d_ws, size_t ws_size,
                              hipStream_t stream) {
    const int*   shape_id = (const int*)d_in[0];
    const int*   color_id = (const int*)d_in[1];
    const int*   edge_idx = (const int*)d_in[2];
    const int*   batch    = (const int*)d_in[3];
    const float* st       = (const float*)d_in[4];
    const float* ct       = (const float*)d_in[5];
    const float* W1       = (const float*)d_in[6];
    const float* b1       = (const float*)d_in[7];
    const float* W2       = (const float*)d_in[8];
    const float* b2       = (const float*)d_in[9];
    const float* Wl       = (const float*)d_in[10];
    const float* bl       = (const float*)d_in[11];
    float* out = (float*)d_out;

    const int* src = edge_idx;
    const int* dst = edge_idx + N_EDGES;

    // workspace layout (512B-aligned)
    char* ws = (char*)d_ws;
    int*   pk     = (int*)  (ws + 0);            //   400,000 B
    float* dis    = (float*)(ws + 400384);       //   400,000 B
    int*   degi   = (int*)  (ws + 800768);       //   400,000 B
    int*   rowptr = (int*)  (ws + 1201152);      //   400,004 B
    int*   cursor = (int*)  (ws + 1601536);      //   400,000 B
    int*   bsum   = (int*)  (ws + 2001920);      //     2,048 B
    float* TC     = (float*)(ws + 2003968);      //    39,168 B
    float* pooled = (float*)(ws + 2043136);      //   262,144 B
    int*   cnt    = (int*)  (ws + 2305280);      //     4,096 B
    int*   epack  = (int*)  (ws + 2309376);      // 6,400,000 B (exact CSR, 4B records)
    float* x1h2   = (float*)(ws + 8709376);      // 25,600,000 B  (total ~34.3 MB)

    hipMemsetAsync(degi, 0, N_NODES * sizeof(int), stream);
    hipMemsetAsync(pooled, 0, N_GRAPHS * HID * sizeof(float) + N_GRAPHS * sizeof(int), stream);

    // 1. degrees
    deg_kernel<<<(N_EDGES + 255) / 256, 256, 0, stream>>>(dst, degi);

    // 2. per-node key + norm + per-graph counts
    prep_kernel<<<SCAN_BLOCKS, 256, 0, stream>>>(degi, shape_id, color_id, batch, pk, dis, cnt);

    // 3. combined (shape,color)->h1 table
    tc_kernel<<<NCOMBO, 64, 0, stream>>>(st, ct, W1, TC);

    // 4. exclusive scan -> rowptr, cursor
    scanA_kernel<<<SCAN_BLOCKS, 256, 0, stream>>>(degi, rowptr, bsum);
    scanB_kernel<<<1, 512, 0, stream>>>(bsum);
    scanC_kernel<<<SCAN_BLOCKS, 256, 0, stream>>>(rowptr, cursor, bsum);

    // 5. CSR fill, 8 dst-range passes for write locality
    {
        dim3 grid(N_EDGES / 256, NPASS, 1);
        fill_kernel<<<grid, 256, 0, stream>>>(src, dst, pk, cursor, epack);
    }

    // 6. layer-1 aggregate -> x1
    agg1_kernel<<<6250, 256, 0, stream>>>(epack, rowptr, pk, dis, TC, b1, x1h2);

    // 7. x1 @ W2 in place -> h2
    mm2_kernel<<<1563, 256, 0, stream>>>(x1h2, W2);

    // 8. layer-2 aggregate + pool
    agg2_pool_kernel<<<N_NODES / 4, 256, 0, stream>>>(epack, rowptr, x1h2, dis, b2, batch, pooled);

    // 9. logits
    logits_kernel<<<N_GRAPHS, 64, 0, stream>>>(pooled, cnt, Wl, bl, out);
}

// Round 6
// 386.329 us; speedup vs baseline: 1.1802x; 1.1802x over previous
//
#include <hip/hip_runtime.h>
#include <hip/hip_bf16.h>

#define N_NODES   100000
#define N_EDGES   1600000
#define N_GRAPHS  1024
#define EMB       32
#define HID       64
#define N_CLASSES 10
#define SCAN_BLOCKS 391   // ceil(100000/256)
#define NCOMBO 153        // 17 shape ids x 9 color ids
#define BUCK_NODES 448    // nodes per dst-bucket
#define NBUCK 224         // ceil(100000/448)
#define BIN_CAP 8192      // per-bucket staging capacity (mean 7168, sigma ~85)
#define EPB 8192          // edges per binA block

// ---------------- degree count (in-degree over dst) ----------------
__global__ __launch_bounds__(256) void deg_kernel(const int* __restrict__ dst,
                                                  int* __restrict__ degi) {
    int e = blockIdx.x * 256 + threadIdx.x;
    if (e < N_EDGES) atomicAdd(&degi[dst[e]], 1);
}

// ---------------- prep: combo[v], dis[v], per-graph counts ----------------
__global__ __launch_bounds__(256) void prep_kernel(
    const int* __restrict__ degi, const int* __restrict__ sid,
    const int* __restrict__ cid, const int* __restrict__ batch,
    int* __restrict__ combo, float* __restrict__ dis, int* __restrict__ cnt) {
    int v = blockIdx.x * 256 + threadIdx.x;
    if (v < N_NODES) {
        dis[v] = rsqrtf(1.0f + (float)degi[v]);
        combo[v] = sid[v] * 9 + cid[v];
        atomicAdd(&cnt[batch[v]], 1);
    }
}

// ---------------- combined table: TC[s*9+c][j] = (st[s]@W1)[j] + (ct[c]@W1)[j] ----------------
__global__ __launch_bounds__(64) void tc_kernel(
    const float* __restrict__ st, const float* __restrict__ ct,
    const float* __restrict__ W1, float* __restrict__ TC) {
    int r = blockIdx.x, j = threadIdx.x;
    int s = r / 9, c = r % 9;
    float acc = 0.0f;
    if (s != 0) {
#pragma unroll
        for (int k = 0; k < EMB; ++k) acc = fmaf(st[s * EMB + k], W1[k * HID + j], acc);
    }
    if (c != 0) {
#pragma unroll
        for (int k = 0; k < EMB; ++k) acc = fmaf(ct[c * EMB + k], W1[k * HID + j], acc);
    }
    TC[r * HID + j] = acc;
}

// ---------------- 3-pass exclusive scan of degrees -> rowptr ----------------
__global__ __launch_bounds__(256) void scanA_kernel(const int* __restrict__ degi,
                                                    int* __restrict__ rowptr,
                                                    int* __restrict__ bsum) {
    __shared__ int s[256];
    int t = threadIdx.x, b = blockIdx.x;
    int v = b * 256 + t;
    int d = (v < N_NODES) ? degi[v] : 0;
    s[t] = d; __syncthreads();
#pragma unroll
    for (int off = 1; off < 256; off <<= 1) {
        int x = (t >= off) ? s[t - off] : 0;
        __syncthreads();
        s[t] += x;
        __syncthreads();
    }
    if (v < N_NODES) rowptr[v] = s[t] - d;
    if (t == 255) bsum[b] = s[255];
}

__global__ __launch_bounds__(512) void scanB_kernel(int* __restrict__ bsum) {
    __shared__ int s[512];
    int t = threadIdx.x;
    int d = (t < SCAN_BLOCKS) ? bsum[t] : 0;
    s[t] = d; __syncthreads();
#pragma unroll
    for (int off = 1; off < 512; off <<= 1) {
        int x = (t >= off) ? s[t - off] : 0;
        __syncthreads();
        s[t] += x;
        __syncthreads();
    }
    if (t < SCAN_BLOCKS) bsum[t] = s[t] - d;
}

__global__ __launch_bounds__(256) void scanC_kernel(int* __restrict__ rowptr,
                                                    const int* __restrict__ bsum) {
    int t = threadIdx.x, b = blockIdx.x;
    int v = b * 256 + t;
    if (v < N_NODES) rowptr[v] += bsum[b];
    if (b == 0 && t == 0) rowptr[N_NODES] = N_EDGES;
}

// ---------------- binA: block-local counting sort by dst-bucket, chunked flush ----------------
// 512 threads, 8192 edges/block. Staging record: {src | combo<<17, dst}.
__global__ __launch_bounds__(512) void binA_kernel(
    const int* __restrict__ src, const int* __restrict__ dst,
    const int* __restrict__ combo, int* __restrict__ gcur,
    int2* __restrict__ gbin) {
    __shared__ int2 stg[EPB];            // 64 KB
    __shared__ int hist[NBUCK];
    __shared__ int base[NBUCK + 1];
    __shared__ int gstart[NBUCK];
    __shared__ int scanbuf[256];
    int t = threadIdx.x;
    int e0 = blockIdx.x * EPB;
    for (int i = t; i < NBUCK; i += 512) hist[i] = 0;
    __syncthreads();

    int2 myq[16];
    int mybo[16];   // bucket<<16 | offset  (offset < 8192 fits 13 bits; bucket < 224)
#pragma unroll
    for (int i = 0; i < 16; ++i) {
        int e = e0 + t + i * 512;
        if (e < N_EDGES) {
            int d = dst[e];
            int s = src[e];
            unsigned b = (unsigned)d / BUCK_NODES;
            int off = atomicAdd(&hist[b], 1);
            myq[i].x = s | (combo[s] << 17);
            myq[i].y = d;
            mybo[i] = (int)(b << 16) | off;
        } else {
            mybo[i] = -1;
        }
    }
    __syncthreads();

    // exclusive scan of hist (224 entries, padded to 256)
    int h = (t < NBUCK) ? hist[t] : 0;
    if (t < 256) scanbuf[t] = h;
    __syncthreads();
#pragma unroll
    for (int off = 1; off < 256; off <<= 1) {
        int x = (t < 256 && t >= off) ? scanbuf[t - off] : 0;
        __syncthreads();
        if (t < 256) scanbuf[t] += x;
        __syncthreads();
    }
    if (t < NBUCK) base[t] = scanbuf[t] - h;
    if (t == 0) base[NBUCK] = 0;         // placeholder
    __syncthreads();
    if (t == 0) base[NBUCK] = scanbuf[255];   // total valid records
    // scatter into LDS (bucket-sorted)
#pragma unroll
    for (int i = 0; i < 16; ++i) {
        if (mybo[i] >= 0) {
            int b = mybo[i] >> 16, off = mybo[i] & 0xFFFF;
            stg[base[b] + off] = myq[i];
        }
    }
    // reserve global chunks
    if (t < NBUCK) {
        int n = hist[t];
        gstart[t] = n ? atomicAdd(&gcur[t], n) : 0;
    }
    __syncthreads();
    int total = base[NBUCK];
    for (int i = t; i < total; i += 512) {
        int2 q = stg[i];
        unsigned b = (unsigned)q.y / BUCK_NODES;
        gbin[(size_t)b * BIN_CAP + gstart[b] + (i - base[b])] = q;
    }
}

// ---------------- binB: per-bucket fine scatter to CSR (one block per bucket) ----------------
// Final CSR record: {src | combo<<17, bits(dis[src])}. All stores land in one
// ~57 KB window owned by this block -> single-XCD L2, full write merging.
__global__ __launch_bounds__(256) void binB_kernel(
    const int2* __restrict__ gbin, const int* __restrict__ gcur,
    const int* __restrict__ rowptr, const float* __restrict__ dis,
    int2* __restrict__ epack) {
    __shared__ int curs[BUCK_NODES];
    int b = blockIdx.x, t = threadIdx.x;
    for (int i = t; i < BUCK_NODES; i += 256) curs[i] = 0;
    __syncthreads();
    int n = gcur[b];
    const int2* mybin = gbin + (size_t)b * BIN_CAP;
    for (int i = t; i < n; i += 256) {
        int2 q = mybin[i];
        int local = q.y - b * BUCK_NODES;
        int r = atomicAdd(&curs[local], 1);
        int2 rec;
        rec.x = q.x;
        rec.y = __float_as_int(dis[q.x & 0x1FFFF]);
        epack[rowptr[q.y] + r] = rec;
    }
}

// ---------------- layer-1 aggregate from combined table -> x1 ----------------
__global__ __launch_bounds__(256) void agg1_kernel(
    const int2* __restrict__ epack, const int* __restrict__ rowptr,
    const int* __restrict__ combo, const float* __restrict__ dis,
    const float* __restrict__ TC, const float* __restrict__ b1,
    float* __restrict__ x1) {
    __shared__ __align__(16) float TCs[NCOMBO * HID];   // 39,168 B
    int t = threadIdx.x;
    {
        const float4* s4 = (const float4*)TC;
        float4* d4 = (float4*)TCs;
        for (int i = t; i < NCOMBO * HID / 4; i += 256) d4[i] = s4[i];
    }
    __syncthreads();
    int lane = t & 63, w = t >> 6;
    float bias = b1[lane];
    int v0 = (blockIdx.x * 4 + w) * 4;
    for (int n = 0; n < 4; ++n) {
        int v = v0 + n;
        int e  = __builtin_amdgcn_readfirstlane(rowptr[v]);
        int e1 = __builtin_amdgcn_readfirstlane(rowptr[v + 1]);
        float acc = 0.0f;
        for (; e + 8 <= e1; e += 8) {
            int2 q[8];
#pragma unroll
            for (int i = 0; i < 8; ++i) q[i] = epack[e + i];
#pragma unroll
            for (int i = 0; i < 8; ++i)
                acc = fmaf(__int_as_float(q[i].y),
                           TCs[((unsigned)q[i].x >> 17) * HID + lane], acc);
        }
        for (; e < e1; ++e) {
            int2 q = epack[e];
            acc = fmaf(__int_as_float(q.y),
                       TCs[((unsigned)q.x >> 17) * HID + lane], acc);
        }
        float dv = dis[v];
        float hv = TCs[combo[v] * HID + lane];
        float val = dv * fmaf(hv, dv, acc) + bias;
        x1[(size_t)v * HID + lane] = val > 0.0f ? val : 0.0f;
    }
}

// ---------------- mm2 in place: x[v] = x[v] @ W2; W2 column in 64 VGPRs ----------------
__global__ __launch_bounds__(256, 1) void mm2_kernel(float* __restrict__ x,
                                                     const float* __restrict__ W2) {
    __shared__ __align__(16) float xs[4][HID];
    int t = threadIdx.x, lane = t & 63, w = t >> 6;
    float wcol[HID];
#pragma unroll
    for (int k = 0; k < HID; ++k) wcol[k] = W2[k * HID + lane];
    int v0 = (blockIdx.x * 4 + w) * 16;
    for (int n = 0; n < 16; ++n) {
        int v = v0 + n;
        if (v >= N_NODES) return;
        xs[w][lane] = x[(size_t)v * HID + lane];
        float acc = 0.0f;
#pragma unroll
        for (int k4 = 0; k4 < HID / 4; ++k4) {
            float4 xv = *(const float4*)(&xs[w][k4 * 4]);
            acc = fmaf(xv.x, wcol[k4 * 4 + 0], acc);
            acc = fmaf(xv.y, wcol[k4 * 4 + 1], acc);
            acc = fmaf(xv.z, wcol[k4 * 4 + 2], acc);
            acc = fmaf(xv.w, wcol[k4 * 4 + 3], acc);
        }
        x[(size_t)v * HID + lane] = acc;
    }
}

// ---------------- layer-2 aggregate + fused mean-pool accumulation ----------------
__global__ __launch_bounds__(256) void agg2_pool_kernel(
    const int2* __restrict__ epack, const int* __restrict__ rowptr,
    const float* __restrict__ h2, const float* __restrict__ dis,
    const float* __restrict__ b2, const int* __restrict__ batch,
    float* __restrict__ pooled) {
    int t = threadIdx.x, lane = t & 63;
    int v = blockIdx.x * 4 + (t >> 6);
    int e  = __builtin_amdgcn_readfirstlane(rowptr[v]);
    int e1 = __builtin_amdgcn_readfirstlane(rowptr[v + 1]);
    float acc = 0.0f;
    for (; e + 8 <= e1; e += 8) {
        int2 q[8];
#pragma unroll
        for (int i = 0; i < 8; ++i) q[i] = epack[e + i];
        float g[8];
#pragma unroll
        for (int i = 0; i < 8; ++i)
            g[i] = h2[(size_t)(q[i].x & 0x1FFFF) * HID + lane];
#pragma unroll
        for (int i = 0; i < 8; ++i)
            acc = fmaf(__int_as_float(q[i].y), g[i], acc);
    }
    for (; e < e1; ++e) {
        int2 q = epack[e];
        acc = fmaf(__int_as_float(q.y), h2[(size_t)(q.x & 0x1FFFF) * HID + lane], acc);
    }
    float dv = dis[v];
    float val = dv * fmaf(h2[(size_t)v * HID + lane], dv, acc) + b2[lane];
    val = val > 0.0f ? val : 0.0f;
    unsafeAtomicAdd(&pooled[batch[v] * HID + lane], val);
}

// ---------------- logits ----------------
__global__ __launch_bounds__(64) void logits_kernel(
    const float* __restrict__ pooled, const int* __restrict__ cnt,
    const float* __restrict__ Wl, const float* __restrict__ bl,
    float* __restrict__ out) {
    __shared__ float row[HID];
    int g = blockIdx.x, t = threadIdx.x;
    int c = cnt[g]; if (c < 1) c = 1;
    row[t] = pooled[g * HID + t] / (float)c;
    __syncthreads();
    if (t < N_CLASSES) {
        float acc = bl[t];
#pragma unroll
        for (int k = 0; k < HID; ++k) acc = fmaf(row[k], Wl[k * N_CLASSES + t], acc);
        out[g * N_CLASSES + t] = acc;
    }
}

extern "C" void kernel_launch(void* const* d_in, const int* in_sizes, int n_in,
                              void* d_out, int out_size, void* d_ws, size_t ws_size,
                              hipStream_t stream) {
    const int*   shape_id = (const int*)d_in[0];
    const int*   color_id = (const int*)d_in[1];
    const int*   edge_idx = (const int*)d_in[2];
    const int*   batch    = (const int*)d_in[3];
    const float* st       = (const float*)d_in[4];
    const float* ct       = (const float*)d_in[5];
    const float* W1       = (const float*)d_in[6];
    const float* b1       = (const float*)d_in[7];
    const float* W2       = (const float*)d_in[8];
    const float* b2       = (const float*)d_in[9];
    const float* Wl       = (const float*)d_in[10];
    const float* bl       = (const float*)d_in[11];
    float* out = (float*)d_out;

    const int* src = edge_idx;
    const int* dst = edge_idx + N_EDGES;

    // workspace layout (aligned). gbin aliases x1h2 (dead until agg1).
    char* ws = (char*)d_ws;
    int*   combo  = (int*)  (ws + 0);            //   400,384 B
    float* dis    = (float*)(ws + 400384);       //   400,384 B
    int*   degi   = (int*)  (ws + 800768);       //   400,384 B
    int*   rowptr = (int*)  (ws + 1201152);      //   400,384 B
    int*   bsum   = (int*)  (ws + 1601536);      //     2,048 B
    float* TC     = (float*)(ws + 1603584);      //    39,424 B
    float* pooled = (float*)(ws + 1643008);      //   262,144 B
    int*   cnt    = (int*)  (ws + 1905152);      //     4,096 B
    int*   gcur   = (int*)  (ws + 1909248);      //     1,024 B
    int2*  epack  = (int2*) (ws + 1910272);      // 12,800,000 B
    float* x1h2   = (float*)(ws + 14710272);     // 25,600,000 B  (total ~40.3 MB)
    int2*  gbin   = (int2*) x1h2;                // alias: 224*8192*8 = 14.68 MB

    hipMemsetAsync(degi, 0, N_NODES * sizeof(int), stream);
    hipMemsetAsync(pooled, 0, N_GRAPHS * HID * sizeof(float) + N_GRAPHS * sizeof(int), stream);
    hipMemsetAsync(gcur, 0, NBUCK * sizeof(int), stream);

    // 1. degrees
    deg_kernel<<<(N_EDGES + 255) / 256, 256, 0, stream>>>(dst, degi);

    // 2. per-node combo + norm + per-graph counts
    prep_kernel<<<SCAN_BLOCKS, 256, 0, stream>>>(degi, shape_id, color_id, batch,
                                                 combo, dis, cnt);

    // 3. combined (shape,color)->h1 table
    tc_kernel<<<NCOMBO, 64, 0, stream>>>(st, ct, W1, TC);

    // 4. exclusive scan -> rowptr
    scanA_kernel<<<SCAN_BLOCKS, 256, 0, stream>>>(degi, rowptr, bsum);
    scanB_kernel<<<1, 512, 0, stream>>>(bsum);
    scanC_kernel<<<SCAN_BLOCKS, 256, 0, stream>>>(rowptr, bsum);

    // 5. CSR build: bin by bucket (chunked writes), then per-bucket scatter (single-XCD windows)
    binA_kernel<<<(N_EDGES + EPB - 1) / EPB, 512, 0, stream>>>(src, dst, combo, gcur, gbin);
    binB_kernel<<<NBUCK, 256, 0, stream>>>(gbin, gcur, rowptr, dis, epack);

    // 6. layer-1 aggregate -> x1
    agg1_kernel<<<6250, 256, 0, stream>>>(epack, rowptr, combo, dis, TC, b1, x1h2);

    // 7. x1 @ W2 in place -> h2
    mm2_kernel<<<1563, 256, 0, stream>>>(x1h2, W2);

    // 8. layer-2 aggregate + pool
    agg2_pool_kernel<<<N_NODES / 4, 256, 0, stream>>>(epack, rowptr, x1h2, dis, b2,
                                                      batch, pooled);

    // 9. logits
    logits_kernel<<<N_GRAPHS, 64, 0, stream>>>(pooled, cnt, Wl, bl, out);
}